// Round 11
// baseline (132.584 us; speedup 1.0000x reference)
//
#include <hip/hip_runtime.h>
#include <math.h>

namespace {

constexpr int SEQ  = 300;
constexpr int DM   = 64;
constexpr int DFFN = 256;
constexpr int NBAT = 256;
constexpr int ROWS = NBAT * SEQ;   // 76800
constexpr float EPS = 1e-5f;

typedef __attribute__((ext_vector_type(8))) short s16x8;
typedef __attribute__((ext_vector_type(4))) float f32x4;

__device__ __forceinline__ float4 ld4(const float* p) { return *reinterpret_cast<const float4*>(p); }

__device__ __forceinline__ ushort f2bf(float x) {
  unsigned u = __builtin_bit_cast(unsigned, x);
  u += 0x7FFFu + ((u >> 16) & 1u);
  return (ushort)(u >> 16);
}

// ---------------------------------------------------------------------------
// Prep (verified, unchanged)
// ---------------------------------------------------------------------------
struct PrepArgs {
  const float *Wq,*Wk,*Wv,*Wcq,*Wck,*Wcv;
  const float *bq,*bk,*bv,*bcq,*bck,*bcv;
  const float *gQE,*betaQE,*gKE,*betaKE,*gVE,*betaVE;
  const float *gQH,*betaQH,*gKH,*betaKH,*gVH,*betaVH;
  const float *W1,*W2;
  ushort *Bqkv, *W1t, *W2t;
  float *pk;   // bE[192] bH[192] gE[192] betaE[192] gH[192] betaH[192]
};

__global__ __launch_bounds__(256) void tb_prep(PrepArgs P) {
  const int idx = blockIdx.x * 256 + threadIdx.x;
  if (idx < 61440) {                       // Bqkv [5 chunks][192 n][64 k]
    const int c = idx / 12288, rem = idx % 12288;
    const int n = rem >> 6, k = rem & 63;
    const int br = n >> 6, col = n & 63;
    float v;
    if (c == 0) {
      const float* W = (br == 0) ? P.Wq : (br == 1) ? P.Wk : P.Wv;
      v = W[k * DM + col];
    } else {
      const float* W = (br == 0) ? P.Wcq : (br == 1) ? P.Wck : P.Wcv;
      v = W[((c - 1) * 64 + k) * DM + col];
    }
    P.Bqkv[c * 12288 + ((n * 128 + ((k * 2) ^ ((n & 7) << 4))) >> 1)] = f2bf(v);
  } else if (idx < 77824) {                // W1t [256 n][64 k] swizzled rows
    const int r = idx - 61440, n = r >> 6, k = r & 63;
    P.W1t[(n * 128 + ((k * 2) ^ ((n & 7) << 4))) >> 1] = f2bf(P.W1[k * DFFN + n]);
  } else if (idx < 94208) {                // W2t fragments [ps 0..7][nt2 0..3][lane][8]
    const int j = idx - 77824;
    const int fragId = j >> 9, within = j & 511;
    const int lane = within >> 3, e = within & 7;
    const int ps = fragId >> 2, nt2 = fragId & 3;
    const int n = nt2 * 16 + (lane & 15);
    const int k = ps * 32 + ((e >> 2) << 4) + ((lane >> 4) << 2) + (e & 3);
    P.W2t[j] = f2bf(P.W2[k * DM + n]);
  } else if (idx < 95360) {                // packed bias/LN params
    const int r = idx - 94208, which = r / 192, j = r % 192;
    const int br = j >> 6, col = j & 63;
    const float* s;
    switch (which) {
      case 0:  s = (br==0)?P.bq   :(br==1)?P.bk    :P.bv;     break;
      case 1:  s = (br==0)?P.bcq  :(br==1)?P.bck   :P.bcv;    break;
      case 2:  s = (br==0)?P.gQE  :(br==1)?P.gKE   :P.gVE;    break;
      case 3:  s = (br==0)?P.betaQE:(br==1)?P.betaKE:P.betaVE; break;
      case 4:  s = (br==0)?P.gQH  :(br==1)?P.gKH   :P.gVH;    break;
      default: s = (br==0)?P.betaQH:(br==1)?P.betaKH:P.betaVH; break;
    }
    P.pk[which * 192 + j] = s[col];
  }
}

// ---------------------------------------------------------------------------
// K1: q/k/v via MFMA. Changes vs R6-verified (operand bytes to MFMA
// identical, verified by swizzle algebra):
//  (a) A-fragments load directly from global per lane (the A-LDS tile was
//      1-writer/1-reader — pure overhead) with in-register f2bf pack.
//  (b) B double-buffered, fully-unrolled 2-phase loop (catalog T3-minimum):
//      STAGE_B(c+1 -> buf^1); COMPUTE(buf); sync.  One barrier per chunk.
// Epilogue identical to R6 (vbuf aliases Bb[0]).
// ---------------------------------------------------------------------------
struct QkvArgs {
  const float *state, *H;
  const ushort *Bqkv;
  const float *pk;
  ushort *qo, *ko, *vo;  // q,k: [bh][300][32] ; v: [bh][32][300]
};

__global__ __launch_bounds__(256) void tb_qkv(QkvArgs A) {
  __shared__ __align__(16) ushort Bb[2][12288];   // 48KB double-buffered B
  const int t = threadIdx.x;
  const int lane = t & 63, w = t >> 6;
  const int lo = lane & 15, hi = lane >> 4;
  const int rowbase = blockIdx.x * 64;

  f32x4 accE[12], accH[12];
  #pragma unroll
  for (int nt = 0; nt < 12; ++nt) {
    const float bE = A.pk[nt * 16 + lo], bH = A.pk[192 + nt * 16 + lo];
    accE[nt] = (f32x4){bE, bE, bE, bE};
    accH[nt] = (f32x4){bH, bH, bH, bH};
  }

  const int arowg = rowbase + w * 16 + lo;          // this lane's A row (global)
  const float* stp = A.state + (size_t)arowg * 64;
  const float* hp  = A.H + (size_t)arowg * 256;

#define STAGE_B(c, buf)                                                       \
  _Pragma("unroll")                                                           \
  for (int i = 0; i < 6; ++i) {                                               \
    const int s_ = i * 256 + t;                                               \
    *(uint4*)&Bb[buf][s_ * 8] = *(const uint4*)&A.Bqkv[(c) * 12288 + s_ * 8]; \
  }

  STAGE_B(0, 0)
  __syncthreads();

  #pragma unroll
  for (int c = 0; c < 5; ++c) {
    const int cur = c & 1;
    // A fragments direct from global: af(ks) = A[arowg][32ks + 8hi .. +8)
    const float* ap = (c == 0) ? stp : (hp + (c - 1) * 64);
    const float4 a0 = ld4(ap + hi * 8);
    const float4 a1 = ld4(ap + hi * 8 + 4);
    const float4 a2 = ld4(ap + 32 + hi * 8);
    const float4 a3 = ld4(ap + 32 + hi * 8 + 4);
    if (c < 4) { STAGE_B(c + 1, cur ^ 1) }          // overlaps compute below
    struct S8 { ushort4 a, b; } p0, p1;
    p0.a.x = f2bf(a0.x); p0.a.y = f2bf(a0.y); p0.a.z = f2bf(a0.z); p0.a.w = f2bf(a0.w);
    p0.b.x = f2bf(a1.x); p0.b.y = f2bf(a1.y); p0.b.z = f2bf(a1.z); p0.b.w = f2bf(a1.w);
    p1.a.x = f2bf(a2.x); p1.a.y = f2bf(a2.y); p1.a.z = f2bf(a2.z); p1.a.w = f2bf(a2.w);
    p1.b.x = f2bf(a3.x); p1.b.y = f2bf(a3.y); p1.b.z = f2bf(a3.z); p1.b.w = f2bf(a3.w);
    const s16x8 af0 = __builtin_bit_cast(s16x8, p0);
    const s16x8 af1 = __builtin_bit_cast(s16x8, p1);
    const char* bbase = (const char*)&Bb[cur][0];
    if (c == 0) {
      #pragma unroll
      for (int nt = 0; nt < 12; ++nt) {
        const int n_ = nt * 16 + lo;
        const s16x8 bf0 = *(const s16x8*)(bbase + (n_ * 128 + ((hi * 16) ^ ((n_ & 7) << 4))));
        accE[nt] = __builtin_amdgcn_mfma_f32_16x16x32_bf16(af0, bf0, accE[nt], 0, 0, 0);
        const s16x8 bf1 = *(const s16x8*)(bbase + (n_ * 128 + ((64 + hi * 16) ^ ((n_ & 7) << 4))));
        accE[nt] = __builtin_amdgcn_mfma_f32_16x16x32_bf16(af1, bf1, accE[nt], 0, 0, 0);
      }
    } else {
      #pragma unroll
      for (int nt = 0; nt < 12; ++nt) {
        const int n_ = nt * 16 + lo;
        const s16x8 bf0 = *(const s16x8*)(bbase + (n_ * 128 + ((hi * 16) ^ ((n_ & 7) << 4))));
        accH[nt] = __builtin_amdgcn_mfma_f32_16x16x32_bf16(af0, bf0, accH[nt], 0, 0, 0);
        const s16x8 bf1 = *(const s16x8*)(bbase + (n_ * 128 + ((64 + hi * 16) ^ ((n_ & 7) << 4))));
        accH[nt] = __builtin_amdgcn_mfma_f32_16x16x32_bf16(af1, bf1, accH[nt], 0, 0, 0);
      }
    }
    __syncthreads();
  }
#undef STAGE_B

  // epilogue (R6 formulas): dual LN + gate, q/k scalar stores, v via LDS xpose
  const float* gE  = A.pk + 384;
  const float* bEt = A.pk + 576;
  const float* gH  = A.pk + 768;
  const float* bHt = A.pk + 960;
  const int growbase = rowbase + w * 16 + hi * 4;
  float vout[4][4];

  #pragma unroll
  for (int br = 0; br < 3; ++br) {
    #pragma unroll
    for (int r = 0; r < 4; ++r) {
      float s1 = 0.f, s2 = 0.f, u1 = 0.f, u2 = 0.f;
      #pragma unroll
      for (int qq = 0; qq < 4; ++qq) {
        const float ev = accE[br * 4 + qq][r], hv = accH[br * 4 + qq][r];
        s1 += ev; s2 += ev * ev; u1 += hv; u2 += hv * hv;
      }
      #pragma unroll
      for (int m = 1; m <= 8; m <<= 1) {
        s1 += __shfl_xor(s1, m, 64); s2 += __shfl_xor(s2, m, 64);
        u1 += __shfl_xor(u1, m, 64); u2 += __shfl_xor(u2, m, 64);
      }
      const float me = s1 * (1.f / 64.f);
      const float re = rsqrtf(s2 * (1.f / 64.f) - me * me + EPS);
      const float mh = u1 * (1.f / 64.f);
      const float rh = rsqrtf(u2 * (1.f / 64.f) - mh * mh + EPS);
      const int grow = growbase + r;
      const int bb = grow / 300, ss = grow - bb * 300;
      #pragma unroll
      for (int qq = 0; qq < 4; ++qq) {
        const int colg = (br * 4 + qq) * 16 + lo;
        const float en = (accE[br * 4 + qq][r] - me) * re * gE[colg] + bEt[colg];
        const float hn = (accH[br * 4 + qq][r] - mh) * rh * gH[colg] + bHt[colg];
        const float val = en * hn;
        if (br == 2) {
          vout[r][qq] = val;
        } else {
          const int cb = qq * 16 + lo;
          const int hh = cb >> 5, dk = cb & 31;
          ushort* dst = (br == 0) ? A.qo : A.ko;
          const float sc = (br == 0) ? 0.17677669529663687f : 1.f;
          dst[((size_t)(bb * 2 + hh) * 300 + ss) * 32 + dk] = f2bf(val * sc);
        }
      }
    }
  }

  __syncthreads();
  ushort* vbuf = &Bb[0][0];  // [64 dk][68 s] (aliases B buffers; reads done)
  #pragma unroll
  for (int r = 0; r < 4; ++r) {
    const int sl = w * 16 + hi * 4 + r;
    #pragma unroll
    for (int qq = 0; qq < 4; ++qq) {
      const int dk = qq * 16 + lo;
      vbuf[dk * 68 + sl] = f2bf(vout[r][qq]);
    }
  }
  __syncthreads();
  #pragma unroll
  for (int i = 0; i < 4; ++i) {
    const int p = i * 256 + t;
    const int dk = p >> 4, sg = p & 15;
    const int grow = rowbase + sg * 4;
    const int bb = grow / 300, ss = grow - bb * 300;
    const int hh = dk >> 5, dkh = dk & 31;
    ushort4 val;
    val.x = vbuf[dk * 68 + sg * 4 + 0];
    val.y = vbuf[dk * 68 + sg * 4 + 1];
    val.z = vbuf[dk * 68 + sg * 4 + 2];
    val.w = vbuf[dk * 68 + sg * 4 + 3];
    *(ushort4*)&A.vo[(size_t)(bb * 2 + hh) * 9600 + dkh * 300 + ss] = val;
  }
}

// ---------------------------------------------------------------------------
// K2: bf16 MFMA attention (R10-verified, unchanged: Q direct from global).
// ---------------------------------------------------------------------------
__global__ __launch_bounds__(256, 2) void tb_attn(const ushort* __restrict__ q,
    const ushort* __restrict__ k, const ushort* __restrict__ vt, float* __restrict__ ao)
{
  __shared__ __align__(16) char lk[304 * 64];
  __shared__ __align__(16) char lv[32 * 656];

  const int t = threadIdx.x;
  const int hh = blockIdx.x, b = blockIdx.y;
  const size_t bh = (size_t)(b * 2 + hh);

  const char* qg = (const char*)(q + bh * 300 * 32);
  const char* kg = (const char*)(k + bh * 300 * 32);
  const char* vg = (const char*)(vt + bh * 32 * 300);

  for (int c = t; c < 1216; c += 256) {
    const int lin = c * 16;
    const int row = c >> 2;
    uint4 val = make_uint4(0u, 0u, 0u, 0u);
    if (row < 300) val = *(const uint4*)(kg + lin);
    *(uint4*)(lk + (lin ^ ((lin >> 2) & 0x70))) = val;
  }
  for (int i = t; i < 320; i += 256) {
    const int row = i / 10, cc = i - row * 10;
    *(unsigned*)(lv + row * 656 + 600 + cc * 4) = 0u;
  }
  for (int i = t; i < 2400; i += 256) {
    const int row = i / 75, cc = i - row * 75;
    *(uint2*)(lv + row * 656 + cc * 8) = *(const uint2*)(vg + row * 600 + cc * 8);
  }
  __syncthreads();

  const int lane = t & 63, wid = t >> 6;
  const int lo = lane & 15, hi = lane >> 4;
  const f32x4 zero = {0.f, 0.f, 0.f, 0.f};

  for (int qt = wid; qt < 19; qt += 4) {
    const int qrow = qt * 16 + lo;
    s16x8 qf = __builtin_bit_cast(s16x8, make_uint4(0u, 0u, 0u, 0u));
    if (qrow < 300) qf = *(const s16x8*)(qg + qrow * 64 + hi * 16);

    f32x4 p[19];
    #pragma unroll
    for (int kt = 0; kt < 19; ++kt) {
      int ka = (kt * 16 + lo) * 64 + hi * 16;
      ka ^= (ka >> 2) & 0x70;
      const s16x8 kf = *(const s16x8*)(lk + ka);
      p[kt] = __builtin_amdgcn_mfma_f32_16x16x32_bf16(kf, qf, zero, 0, 0, 0);
    }

    float mx = -1e30f;
    #pragma unroll
    for (int kt = 0; kt < 19; ++kt)
      #pragma unroll
      for (int r = 0; r < 4; ++r) mx = fmaxf(mx, p[kt][r]);
    mx = fmaxf(mx, __shfl_xor(mx, 16, 64));
    mx = fmaxf(mx, __shfl_xor(mx, 32, 64));

    #pragma unroll
    for (int kt = 0; kt < 19; ++kt)
      #pragma unroll
      for (int r = 0; r < 4; ++r) p[kt][r] = __expf(p[kt][r] - mx);
    if (hi == 3) p[18] = zero;

    float sum = 0.f;
    #pragma unroll
    for (int kt = 0; kt < 19; ++kt)
      #pragma unroll
      for (int r = 0; r < 4; ++r) sum += p[kt][r];
    sum += __shfl_xor(sum, 16, 64);
    sum += __shfl_xor(sum, 32, 64);
    const float inv = 1.f / sum;

    s16x8 pb[10];
    #pragma unroll
    for (int pr = 0; pr < 9; ++pr) {
      uint4 wv;
      wv.x = (unsigned)f2bf(p[2*pr][0] * inv)   | ((unsigned)f2bf(p[2*pr][1] * inv) << 16);
      wv.y = (unsigned)f2bf(p[2*pr][2] * inv)   | ((unsigned)f2bf(p[2*pr][3] * inv) << 16);
      wv.z = (unsigned)f2bf(p[2*pr+1][0] * inv) | ((unsigned)f2bf(p[2*pr+1][1] * inv) << 16);
      wv.w = (unsigned)f2bf(p[2*pr+1][2] * inv) | ((unsigned)f2bf(p[2*pr+1][3] * inv) << 16);
      pb[pr] = __builtin_bit_cast(s16x8, wv);
    }
    {
      uint4 wv;
      wv.x = (unsigned)f2bf(p[18][0] * inv) | ((unsigned)f2bf(p[18][1] * inv) << 16);
      wv.y = (unsigned)f2bf(p[18][2] * inv) | ((unsigned)f2bf(p[18][3] * inv) << 16);
      wv.z = 0u; wv.w = 0u;
      pb[9] = __builtin_bit_cast(s16x8, wv);
    }

    f32x4 acc0 = zero, acc1 = zero;
    #pragma unroll
    for (int pr = 0; pr < 10; ++pr) {
      const int byte0 = pr * 64 + hi * 8;
      uint4 w0, w1;
      {
        const uint2 a = *(const uint2*)(lv + lo * 656 + byte0);
        const uint2 c = *(const uint2*)(lv + lo * 656 + byte0 + 32);
        w0.x = a.x; w0.y = a.y; w0.z = c.x; w0.w = c.y;
      }
      {
        const uint2 a = *(const uint2*)(lv + (lo + 16) * 656 + byte0);
        const uint2 c = *(const uint2*)(lv + (lo + 16) * 656 + byte0 + 32);
        w1.x = a.x; w1.y = a.y; w1.z = c.x; w1.w = c.y;
      }
      acc0 = __builtin_amdgcn_mfma_f32_16x16x32_bf16(pb[pr], __builtin_bit_cast(s16x8, w0), acc0, 0, 0, 0);
      acc1 = __builtin_amdgcn_mfma_f32_16x16x32_bf16(pb[pr], __builtin_bit_cast(s16x8, w1), acc1, 0, 0, 0);
    }

    float* aop = ao + ((size_t)b * 300) * 64 + hh * 32;
    const int s0 = qt * 16 + hi * 4;
    #pragma unroll
    for (int r = 0; r < 4; ++r) {
      const int s = s0 + r;
      if (s < 300) {
        aop[s * 64 + lo]      = acc0[r];
        aop[s * 64 + 16 + lo] = acc1[r];
      }
    }
  }
}

// ---------------------------------------------------------------------------
// K3: FFN via MFMA (verified, unchanged).
// ---------------------------------------------------------------------------
struct FfnArgs {
  const float *state, *ao;
  const ushort *W1t, *W2t;
  const float *b1, *b2, *g1, *beta1;
  float* out;
};

__global__ __launch_bounds__(256) void tb_ffn(FfnArgs F) {
  __shared__ __align__(16) ushort Z2b[4096];    // [64][64] swizzled (8KB), wave-private rows
  __shared__ __align__(16) ushort Wb[16384];    // W1t, then W2 fragments (32KB)
  const int t = threadIdx.x;
  const int lane = t & 63, w = t >> 6;
  const int lo = lane & 15, hi = lane >> 4;
  const int rowbase = blockIdx.x * 64;

  #pragma unroll
  for (int i = 0; i < 8; ++i) {
    const int s_ = i * 256 + t;
    *(uint4*)&Wb[s_ * 8] = *(const uint4*)&F.W1t[s_ * 8];
  }

  {
    const int lrow = t >> 2;
    const int lcg  = (t & 3) * 16;
    const size_t gb = (size_t)(rowbase + lrow) * 64 + lcg;
    float xv[16];
    #pragma unroll
    for (int i = 0; i < 4; ++i) {
      const float4 a = ld4(&F.state[gb + i * 4]);
      const float4 b = ld4(&F.ao[gb + i * 4]);
      xv[i*4+0] = a.x + b.x; xv[i*4+1] = a.y + b.y;
      xv[i*4+2] = a.z + b.z; xv[i*4+3] = a.w + b.w;
    }
    float s1 = 0.f, s2 = 0.f;
    #pragma unroll
    for (int j = 0; j < 16; ++j) { s1 += xv[j]; s2 += xv[j] * xv[j]; }
    s1 += __shfl_xor(s1, 1, 64); s2 += __shfl_xor(s2, 1, 64);
    s1 += __shfl_xor(s1, 2, 64); s2 += __shfl_xor(s2, 2, 64);
    const float mean = s1 * (1.f / 64.f);
    const float rstd = rsqrtf(s2 * (1.f / 64.f) - mean * mean + EPS);
    float gv[16], bv[16];
    #pragma unroll
    for (int i = 0; i < 4; ++i) {
      *(float4*)&gv[i*4] = ld4(&F.g1[lcg + i * 4]);
      *(float4*)&bv[i*4] = ld4(&F.beta1[lcg + i * 4]);
    }
    #pragma unroll
    for (int h = 0; h < 2; ++h) {
      float z[8];
      #pragma unroll
      for (int j = 0; j < 8; ++j)
        z[j] = (xv[h*8+j] - mean) * rstd * gv[h*8+j] + bv[h*8+j];
      uint4 pkd;
      pkd.x = (unsigned)f2bf(z[0]) | ((unsigned)f2bf(z[1]) << 16);
      pkd.y = (unsigned)f2bf(z[2]) | ((unsigned)f2bf(z[3]) << 16);
      pkd.z = (unsigned)f2bf(z[4]) | ((unsigned)f2bf(z[5]) << 16);
      pkd.w = (unsigned)f2bf(z[6]) | ((unsigned)f2bf(z[7]) << 16);
      *(uint4*)((char*)Z2b + (lrow * 128 + (((lcg + h * 8) * 2) ^ ((lrow & 7) << 4)))) = pkd;
    }
  }
  __syncthreads();

  const int arow = w * 16 + lo;
  const int aswz = (lo & 7) << 4;

  s16x8 zf0, zf1;
  zf0 = *(const s16x8*)((const char*)Z2b + (arow * 128 + ((0 * 64 + hi * 16) ^ aswz)));
  zf1 = *(const s16x8*)((const char*)Z2b + (arow * 128 + ((1 * 64 + hi * 16) ^ aswz)));

  s16x8 pz[8];
  #pragma unroll
  for (int ps = 0; ps < 8; ++ps) {
    const int n0 = (2 * ps) * 16, n1 = (2 * ps + 1) * 16;
    const float4 bb0 = ld4(&F.b1[n0 + hi * 4]);
    const float4 bb1 = ld4(&F.b1[n1 + hi * 4]);
    f32x4 a0 = (f32x4){bb0.x, bb0.y, bb0.z, bb0.w};
    f32x4 a1 = (f32x4){bb1.x, bb1.y, bb1.z, bb1.w};
    #pragma unroll
    for (int ks = 0; ks < 2; ++ks) {
      const s16x8 zf = ks ? zf1 : zf0;
      const int na = n0 + lo, nb = n1 + lo;
      const s16x8 wfa = *(const s16x8*)((const char*)Wb + (na * 128 + ((ks * 64 + hi * 16) ^ ((na & 7) << 4))));
      const s16x8 wfb = *(const s16x8*)((const char*)Wb + (nb * 128 + ((ks * 64 + hi * 16) ^ ((nb & 7) << 4))));
      a0 = __builtin_amdgcn_mfma_f32_16x16x32_bf16(wfa, zf, a0, 0, 0, 0);
      a1 = __builtin_amdgcn_mfma_f32_16x16x32_bf16(wfb, zf, a1, 0, 0, 0);
    }
    float ga[8];
    #pragma unroll
    for (int e = 0; e < 8; ++e) {
      const float xg = (e < 4) ? a0[e & 3] : a1[e & 3];
      ga[e] = 0.5f * xg * (1.f + erff(xg * 0.70710678118654752f));
    }
    uint4 wv;
    wv.x = (unsigned)f2bf(ga[0]) | ((unsigned)f2bf(ga[1]) << 16);
    wv.y = (unsigned)f2bf(ga[2]) | ((unsigned)f2bf(ga[3]) << 16);
    wv.z = (unsigned)f2bf(ga[4]) | ((unsigned)f2bf(ga[5]) << 16);
    wv.w = (unsigned)f2bf(ga[6]) | ((unsigned)f2bf(ga[7]) << 16);
    pz[ps] = __builtin_bit_cast(s16x8, wv);
  }
  __syncthreads();

  #pragma unroll
  for (int i = 0; i < 8; ++i) {
    const int s_ = i * 256 + t;
    *(uint4*)&Wb[s_ * 8] = *(const uint4*)&F.W2t[s_ * 8];
  }
  __syncthreads();

  f32x4 acc2[4];
  #pragma unroll
  for (int nt = 0; nt < 4; ++nt) { const float b = F.b2[nt * 16 + lo]; acc2[nt] = (f32x4){b, b, b, b}; }
  #pragma unroll
  for (int ps = 0; ps < 8; ++ps) {
    #pragma unroll
    for (int nt = 0; nt < 4; ++nt) {
      const s16x8 bf = *(const s16x8*)&Wb[((ps * 4 + nt) * 64 + lane) * 8];
      acc2[nt] = __builtin_amdgcn_mfma_f32_16x16x32_bf16(pz[ps], bf, acc2[nt], 0, 0, 0);
    }
  }

  #pragma unroll
  for (int nt = 0; nt < 4; ++nt) {
    #pragma unroll
    for (int r = 0; r < 4; ++r) {
      const int grow = rowbase + w * 16 + hi * 4 + r;
      const int col = nt * 16 + lo;
      const size_t gidx = (size_t)grow * 64 + col;
      const float z1 = F.state[gidx] + F.ao[gidx];
      F.out[gidx] = z1 + acc2[nt][r];
    }
  }
}

} // namespace

extern "C" void kernel_launch(void* const* d_in, const int* in_sizes, int n_in,
                              void* d_out, int out_size, void* d_ws, size_t ws_size,
                              hipStream_t stream)
{
  const float* state = (const float*)d_in[0];
  const float* H     = (const float*)d_in[1];
  const float* Wq  = (const float*)d_in[2];  const float* bq  = (const float*)d_in[3];
  const float* Wk  = (const float*)d_in[4];  const float* bk  = (const float*)d_in[5];
  const float* Wv  = (const float*)d_in[6];  const float* bv  = (const float*)d_in[7];
  const float* Wcq = (const float*)d_in[8];  const float* bcq = (const float*)d_in[9];
  const float* Wck = (const float*)d_in[10]; const float* bck = (const float*)d_in[11];
  const float* Wcv = (const float*)d_in[12]; const float* bcv = (const float*)d_in[13];
  const float* gQE = (const float*)d_in[14]; const float* betaQE = (const float*)d_in[15];
  const float* gKE = (const float*)d_in[16]; const float* betaKE = (const float*)d_in[17];
  const float* gVE = (const float*)d_in[18]; const float* betaVE = (const float*)d_in[19];
  const float* gQH = (const float*)d_in[20]; const float* betaQH = (const float*)d_in[21];
  const float* gKH = (const float*)d_in[22]; const float* betaKH = (const float*)d_in[23];
  const float* gVH = (const float*)d_in[24]; const float* betaVH = (const float*)d_in[25];
  const float* W1 = (const float*)d_in[26]; const float* b1 = (const float*)d_in[27];
  const float* W2 = (const float*)d_in[28]; const float* b2 = (const float*)d_in[29];
  const float* g1 = (const float*)d_in[30]; const float* beta1 = (const float*)d_in[31];

  constexpr size_t QKV_E = (size_t)NBAT * 2 * 300 * 32;   // 4,915,200 bf16 per tensor
  float*  ao_ws = (float*)d_ws;                           // [ROWS][64] fp32
  ushort* q_ws  = (ushort*)(ao_ws + (size_t)ROWS * DM);
  ushort* k_ws  = q_ws + QKV_E;
  ushort* v_ws  = k_ws + QKV_E;
  ushort* Bqkv  = v_ws + QKV_E;        // 61440
  ushort* W1t   = Bqkv + 61440;        // 16384
  ushort* W2t   = W1t + 16384;         // 16384
  float*  pk    = (float*)(W2t + 16384);  // 1152 floats

  PrepArgs P;
  P.Wq = Wq; P.Wk = Wk; P.Wv = Wv; P.Wcq = Wcq; P.Wck = Wck; P.Wcv = Wcv;
  P.bq = bq; P.bk = bk; P.bv = bv; P.bcq = bcq; P.bck = bck; P.bcv = bcv;
  P.gQE = gQE; P.betaQE = betaQE; P.gKE = gKE; P.betaKE = betaKE;
  P.gVE = gVE; P.betaVE = betaVE; P.gQH = gQH; P.betaQH = betaQH;
  P.gKH = gKH; P.betaKH = betaKH; P.gVH = gVH; P.betaVH = betaVH;
  P.W1 = W1; P.W2 = W2;
  P.Bqkv = Bqkv; P.W1t = W1t; P.W2t = W2t; P.pk = pk;
  tb_prep<<<373, 256, 0, stream>>>(P);

  QkvArgs A;
  A.state = state; A.H = H; A.Bqkv = Bqkv; A.pk = pk;
  A.qo = q_ws; A.ko = k_ws; A.vo = v_ws;
  tb_qkv<<<ROWS / 64, 256, 0, stream>>>(A);

  tb_attn<<<dim3(2, NBAT), 256, 0, stream>>>(q_ws, k_ws, v_ws, ao_ws);

  FfnArgs F;
  F.state = state; F.ao = ao_ws; F.W1t = W1t; F.W2t = W2t;
  F.b1 = b1; F.b2 = b2; F.g1 = g1; F.beta1 = beta1; F.out = (float*)d_out;
  tb_ffn<<<ROWS / 64, 256, 0, stream>>>(F);
}

// Round 12
// 126.793 us; speedup vs baseline: 1.0457x; 1.0457x over previous
//
#include <hip/hip_runtime.h>
#include <math.h>

namespace {

constexpr int SEQ  = 300;
constexpr int DM   = 64;
constexpr int DFFN = 256;
constexpr int NBAT = 256;
constexpr int ROWS = NBAT * SEQ;   // 76800
constexpr float EPS = 1e-5f;

typedef __attribute__((ext_vector_type(8))) short s16x8;
typedef __attribute__((ext_vector_type(4))) float f32x4;

__device__ __forceinline__ float4 ld4(const float* p) { return *reinterpret_cast<const float4*>(p); }

__device__ __forceinline__ ushort f2bf(float x) {
  unsigned u = __builtin_bit_cast(unsigned, x);
  u += 0x7FFFu + ((u >> 16) & 1u);
  return (ushort)(u >> 16);
}

// ---------------------------------------------------------------------------
// Prep (verified, unchanged)
// ---------------------------------------------------------------------------
struct PrepArgs {
  const float *Wq,*Wk,*Wv,*Wcq,*Wck,*Wcv;
  const float *bq,*bk,*bv,*bcq,*bck,*bcv;
  const float *gQE,*betaQE,*gKE,*betaKE,*gVE,*betaVE;
  const float *gQH,*betaQH,*gKH,*betaKH,*gVH,*betaVH;
  const float *W1,*W2;
  ushort *Bqkv, *W1t, *W2t;
  float *pk;   // bE[192] bH[192] gE[192] betaE[192] gH[192] betaH[192]
};

__global__ __launch_bounds__(256) void tb_prep(PrepArgs P) {
  const int idx = blockIdx.x * 256 + threadIdx.x;
  if (idx < 61440) {                       // Bqkv [5 chunks][192 n][64 k]
    const int c = idx / 12288, rem = idx % 12288;
    const int n = rem >> 6, k = rem & 63;
    const int br = n >> 6, col = n & 63;
    float v;
    if (c == 0) {
      const float* W = (br == 0) ? P.Wq : (br == 1) ? P.Wk : P.Wv;
      v = W[k * DM + col];
    } else {
      const float* W = (br == 0) ? P.Wcq : (br == 1) ? P.Wck : P.Wcv;
      v = W[((c - 1) * 64 + k) * DM + col];
    }
    P.Bqkv[c * 12288 + ((n * 128 + ((k * 2) ^ ((n & 7) << 4))) >> 1)] = f2bf(v);
  } else if (idx < 77824) {                // W1t [256 n][64 k] swizzled rows
    const int r = idx - 61440, n = r >> 6, k = r & 63;
    P.W1t[(n * 128 + ((k * 2) ^ ((n & 7) << 4))) >> 1] = f2bf(P.W1[k * DFFN + n]);
  } else if (idx < 94208) {                // W2t fragments [ps 0..7][nt2 0..3][lane][8]
    const int j = idx - 77824;
    const int fragId = j >> 9, within = j & 511;
    const int lane = within >> 3, e = within & 7;
    const int ps = fragId >> 2, nt2 = fragId & 3;
    const int n = nt2 * 16 + (lane & 15);
    const int k = ps * 32 + ((e >> 2) << 4) + ((lane >> 4) << 2) + (e & 3);
    P.W2t[j] = f2bf(P.W2[k * DM + n]);
  } else if (idx < 95360) {                // packed bias/LN params
    const int r = idx - 94208, which = r / 192, j = r % 192;
    const int br = j >> 6, col = j & 63;
    const float* s;
    switch (which) {
      case 0:  s = (br==0)?P.bq   :(br==1)?P.bk    :P.bv;     break;
      case 1:  s = (br==0)?P.bcq  :(br==1)?P.bck   :P.bcv;    break;
      case 2:  s = (br==0)?P.gQE  :(br==1)?P.gKE   :P.gVE;    break;
      case 3:  s = (br==0)?P.betaQE:(br==1)?P.betaKE:P.betaVE; break;
      case 4:  s = (br==0)?P.gQH  :(br==1)?P.gKH   :P.gVH;    break;
      default: s = (br==0)?P.betaQH:(br==1)?P.betaKH:P.betaVH; break;
    }
    P.pk[which * 192 + j] = s[col];
  }
}

// ---------------------------------------------------------------------------
// K1: q/k/v via MFMA (R6-verified, byte-identical).
// ---------------------------------------------------------------------------
struct QkvArgs {
  const float *state, *H;
  const ushort *Bqkv;
  const float *pk;
  ushort *qo, *ko, *vo;  // q,k: [bh][300][32] ; v: [bh][32][300]
};

__global__ __launch_bounds__(256) void tb_qkv(QkvArgs A) {
  __shared__ __align__(16) ushort Ab[4608];    // A chunk [64][64] swizzled (+V xpose buf)
  __shared__ __align__(16) ushort Bb[12288];   // B chunk [192][64] swizzled
  const int t = threadIdx.x;
  const int lane = t & 63, w = t >> 6;
  const int lo = lane & 15, hi = lane >> 4;
  const int rowbase = blockIdx.x * 64;

  f32x4 accE[12], accH[12];
  #pragma unroll
  for (int nt = 0; nt < 12; ++nt) {
    const float bE = A.pk[nt * 16 + lo], bH = A.pk[192 + nt * 16 + lo];
    accE[nt] = (f32x4){bE, bE, bE, bE};
    accH[nt] = (f32x4){bH, bH, bH, bH};
  }

  const int arow = w * 16 + lo;
  const int aswz = (lo & 7) << 4;

#define STAGE_B(c)                                                            \
  _Pragma("unroll")                                                           \
  for (int i = 0; i < 6; ++i) {                                               \
    const int s_ = i * 256 + t;                                               \
    *(uint4*)&Bb[s_ * 8] = *(const uint4*)&A.Bqkv[(c) * 12288 + s_ * 8];      \
  }

#define STAGE_A(SRC, STRIDE)                                                  \
  _Pragma("unroll")                                                           \
  for (int i = 0; i < 4; ++i) {                                               \
    const int p_ = i * 256 + t;                                               \
    const int row_ = p_ >> 4, slot_ = p_ & 15;                                \
    const float4 f_ = ld4(&(SRC)[row_ * (STRIDE) + slot_ * 4]);               \
    ushort4 u_;                                                               \
    u_.x = f2bf(f_.x); u_.y = f2bf(f_.y); u_.z = f2bf(f_.z); u_.w = f2bf(f_.w);\
    *(ushort4*)((char*)Ab + (row_ * 128 + ((slot_ * 8) ^ ((row_ & 7) << 4)))) = u_; \
  }

#define COMPUTE(ACC)                                                          \
  _Pragma("unroll")                                                           \
  for (int ks = 0; ks < 2; ++ks) {                                            \
    const s16x8 af = *(const s16x8*)((const char*)Ab +                        \
        (arow * 128 + ((ks * 64 + hi * 16) ^ aswz)));                         \
    _Pragma("unroll")                                                         \
    for (int nt = 0; nt < 12; ++nt) {                                         \
      const int n_ = nt * 16 + lo;                                            \
      const s16x8 bf = *(const s16x8*)((const char*)Bb +                      \
          (n_ * 128 + ((ks * 64 + hi * 16) ^ ((n_ & 7) << 4))));              \
      ACC[nt] = __builtin_amdgcn_mfma_f32_16x16x32_bf16(af, bf, ACC[nt], 0, 0, 0); \
    }                                                                         \
  }

  STAGE_B(0)
  STAGE_A(A.state + (size_t)rowbase * 64, 64)
  __syncthreads();
  COMPUTE(accE)
  for (int c = 1; c < 5; ++c) {
    __syncthreads();
    STAGE_B(c)
    const float* hsrc = A.H + (size_t)rowbase * 256 + (c - 1) * 64;
    STAGE_A(hsrc, 256)
    __syncthreads();
    COMPUTE(accH)
  }
#undef STAGE_B
#undef STAGE_A
#undef COMPUTE

  const float* gE  = A.pk + 384;
  const float* bEt = A.pk + 576;
  const float* gH  = A.pk + 768;
  const float* bHt = A.pk + 960;
  const int growbase = rowbase + w * 16 + hi * 4;
  float vout[4][4];

  #pragma unroll
  for (int br = 0; br < 3; ++br) {
    #pragma unroll
    for (int r = 0; r < 4; ++r) {
      float s1 = 0.f, s2 = 0.f, u1 = 0.f, u2 = 0.f;
      #pragma unroll
      for (int qq = 0; qq < 4; ++qq) {
        const float ev = accE[br * 4 + qq][r], hv = accH[br * 4 + qq][r];
        s1 += ev; s2 += ev * ev; u1 += hv; u2 += hv * hv;
      }
      #pragma unroll
      for (int m = 1; m <= 8; m <<= 1) {
        s1 += __shfl_xor(s1, m, 64); s2 += __shfl_xor(s2, m, 64);
        u1 += __shfl_xor(u1, m, 64); u2 += __shfl_xor(u2, m, 64);
      }
      const float me = s1 * (1.f / 64.f);
      const float re = rsqrtf(s2 * (1.f / 64.f) - me * me + EPS);
      const float mh = u1 * (1.f / 64.f);
      const float rh = rsqrtf(u2 * (1.f / 64.f) - mh * mh + EPS);
      const int grow = growbase + r;
      const int bb = grow / 300, ss = grow - bb * 300;
      #pragma unroll
      for (int qq = 0; qq < 4; ++qq) {
        const int colg = (br * 4 + qq) * 16 + lo;
        const float en = (accE[br * 4 + qq][r] - me) * re * gE[colg] + bEt[colg];
        const float hn = (accH[br * 4 + qq][r] - mh) * rh * gH[colg] + bHt[colg];
        const float val = en * hn;
        if (br == 2) {
          vout[r][qq] = val;
        } else {
          const int cb = qq * 16 + lo;
          const int hh = cb >> 5, dk = cb & 31;
          ushort* dst = (br == 0) ? A.qo : A.ko;
          const float sc = (br == 0) ? 0.17677669529663687f : 1.f;
          dst[((size_t)(bb * 2 + hh) * 300 + ss) * 32 + dk] = f2bf(val * sc);
        }
      }
    }
  }

  __syncthreads();
  ushort* vbuf = Ab;  // [64 dk][68 s]
  #pragma unroll
  for (int r = 0; r < 4; ++r) {
    const int sl = w * 16 + hi * 4 + r;
    #pragma unroll
    for (int qq = 0; qq < 4; ++qq) {
      const int dk = qq * 16 + lo;
      vbuf[dk * 68 + sl] = f2bf(vout[r][qq]);
    }
  }
  __syncthreads();
  #pragma unroll
  for (int i = 0; i < 4; ++i) {
    const int p = i * 256 + t;
    const int dk = p >> 4, sg = p & 15;
    const int grow = rowbase + sg * 4;
    const int bb = grow / 300, ss = grow - bb * 300;
    const int hh = dk >> 5, dkh = dk & 31;
    ushort4 val;
    val.x = vbuf[dk * 68 + sg * 4 + 0];
    val.y = vbuf[dk * 68 + sg * 4 + 1];
    val.z = vbuf[dk * 68 + sg * 4 + 2];
    val.w = vbuf[dk * 68 + sg * 4 + 3];
    *(ushort4*)&A.vo[(size_t)(bb * 2 + hh) * 9600 + dkh * 300 + ss] = val;
  }
}

// ---------------------------------------------------------------------------
// K2: bf16 MFMA attention (R10-verified: Q fragments direct from global,
// 39.5KB LDS). Zero-fill for rows 300..303 via per-lane predication.
// ---------------------------------------------------------------------------
__global__ __launch_bounds__(256, 2) void tb_attn(const ushort* __restrict__ q,
    const ushort* __restrict__ k, const ushort* __restrict__ vt, float* __restrict__ ao)
{
  __shared__ __align__(16) char lk[304 * 64];
  __shared__ __align__(16) char lv[32 * 656];

  const int t = threadIdx.x;
  const int hh = blockIdx.x, b = blockIdx.y;
  const size_t bh = (size_t)(b * 2 + hh);

  const char* qg = (const char*)(q + bh * 300 * 32);
  const char* kg = (const char*)(k + bh * 300 * 32);
  const char* vg = (const char*)(vt + bh * 32 * 300);

  for (int c = t; c < 1216; c += 256) {
    const int lin = c * 16;
    const int row = c >> 2;
    uint4 val = make_uint4(0u, 0u, 0u, 0u);
    if (row < 300) val = *(const uint4*)(kg + lin);
    *(uint4*)(lk + (lin ^ ((lin >> 2) & 0x70))) = val;
  }
  for (int i = t; i < 320; i += 256) {
    const int row = i / 10, cc = i - row * 10;
    *(unsigned*)(lv + row * 656 + 600 + cc * 4) = 0u;
  }
  for (int i = t; i < 2400; i += 256) {
    const int row = i / 75, cc = i - row * 75;
    *(uint2*)(lv + row * 656 + cc * 8) = *(const uint2*)(vg + row * 600 + cc * 8);
  }
  __syncthreads();

  const int lane = t & 63, wid = t >> 6;
  const int lo = lane & 15, hi = lane >> 4;
  const f32x4 zero = {0.f, 0.f, 0.f, 0.f};

  for (int qt = wid; qt < 19; qt += 4) {
    const int qrow = qt * 16 + lo;
    s16x8 qf = __builtin_bit_cast(s16x8, make_uint4(0u, 0u, 0u, 0u));
    if (qrow < 300) qf = *(const s16x8*)(qg + qrow * 64 + hi * 16);

    f32x4 p[19];
    #pragma unroll
    for (int kt = 0; kt < 19; ++kt) {
      int ka = (kt * 16 + lo) * 64 + hi * 16;
      ka ^= (ka >> 2) & 0x70;
      const s16x8 kf = *(const s16x8*)(lk + ka);
      p[kt] = __builtin_amdgcn_mfma_f32_16x16x32_bf16(kf, qf, zero, 0, 0, 0);
    }

    float mx = -1e30f;
    #pragma unroll
    for (int kt = 0; kt < 19; ++kt)
      #pragma unroll
      for (int r = 0; r < 4; ++r) mx = fmaxf(mx, p[kt][r]);
    mx = fmaxf(mx, __shfl_xor(mx, 16, 64));
    mx = fmaxf(mx, __shfl_xor(mx, 32, 64));

    #pragma unroll
    for (int kt = 0; kt < 19; ++kt)
      #pragma unroll
      for (int r = 0; r < 4; ++r) p[kt][r] = __expf(p[kt][r] - mx);
    if (hi == 3) p[18] = zero;

    float sum = 0.f;
    #pragma unroll
    for (int kt = 0; kt < 19; ++kt)
      #pragma unroll
      for (int r = 0; r < 4; ++r) sum += p[kt][r];
    sum += __shfl_xor(sum, 16, 64);
    sum += __shfl_xor(sum, 32, 64);
    const float inv = 1.f / sum;

    s16x8 pb[10];
    #pragma unroll
    for (int pr = 0; pr < 9; ++pr) {
      uint4 wv;
      wv.x = (unsigned)f2bf(p[2*pr][0] * inv)   | ((unsigned)f2bf(p[2*pr][1] * inv) << 16);
      wv.y = (unsigned)f2bf(p[2*pr][2] * inv)   | ((unsigned)f2bf(p[2*pr][3] * inv) << 16);
      wv.z = (unsigned)f2bf(p[2*pr+1][0] * inv) | ((unsigned)f2bf(p[2*pr+1][1] * inv) << 16);
      wv.w = (unsigned)f2bf(p[2*pr+1][2] * inv) | ((unsigned)f2bf(p[2*pr+1][3] * inv) << 16);
      pb[pr] = __builtin_bit_cast(s16x8, wv);
    }
    {
      uint4 wv;
      wv.x = (unsigned)f2bf(p[18][0] * inv) | ((unsigned)f2bf(p[18][1] * inv) << 16);
      wv.y = (unsigned)f2bf(p[18][2] * inv) | ((unsigned)f2bf(p[18][3] * inv) << 16);
      wv.z = 0u; wv.w = 0u;
      pb[9] = __builtin_bit_cast(s16x8, wv);
    }

    f32x4 acc0 = zero, acc1 = zero;
    #pragma unroll
    for (int pr = 0; pr < 10; ++pr) {
      const int byte0 = pr * 64 + hi * 8;
      uint4 w0, w1;
      {
        const uint2 a = *(const uint2*)(lv + lo * 656 + byte0);
        const uint2 c = *(const uint2*)(lv + lo * 656 + byte0 + 32);
        w0.x = a.x; w0.y = a.y; w0.z = c.x; w0.w = c.y;
      }
      {
        const uint2 a = *(const uint2*)(lv + (lo + 16) * 656 + byte0);
        const uint2 c = *(const uint2*)(lv + (lo + 16) * 656 + byte0 + 32);
        w1.x = a.x; w1.y = a.y; w1.z = c.x; w1.w = c.y;
      }
      acc0 = __builtin_amdgcn_mfma_f32_16x16x32_bf16(pb[pr], __builtin_bit_cast(s16x8, w0), acc0, 0, 0, 0);
      acc1 = __builtin_amdgcn_mfma_f32_16x16x32_bf16(pb[pr], __builtin_bit_cast(s16x8, w1), acc1, 0, 0, 0);
    }

    float* aop = ao + ((size_t)b * 300) * 64 + hh * 32;
    const int s0 = qt * 16 + hi * 4;
    #pragma unroll
    for (int r = 0; r < 4; ++r) {
      const int s = s0 + r;
      if (s < 300) {
        aop[s * 64 + lo]      = acc0[r];
        aop[s * 64 + 16 + lo] = acc1[r];
      }
    }
  }
}

// ---------------------------------------------------------------------------
// K3: FFN via MFMA (R6-verified, byte-identical).
// ---------------------------------------------------------------------------
struct FfnArgs {
  const float *state, *ao;
  const ushort *W1t, *W2t;
  const float *b1, *b2, *g1, *beta1;
  float* out;
};

__global__ __launch_bounds__(256) void tb_ffn(FfnArgs F) {
  __shared__ __align__(16) ushort Z2b[4096];    // [64][64] swizzled (8KB), wave-private rows
  __shared__ __align__(16) ushort Wb[16384];    // W1t, then W2 fragments (32KB)
  const int t = threadIdx.x;
  const int lane = t & 63, w = t >> 6;
  const int lo = lane & 15, hi = lane >> 4;
  const int rowbase = blockIdx.x * 64;

  #pragma unroll
  for (int i = 0; i < 8; ++i) {
    const int s_ = i * 256 + t;
    *(uint4*)&Wb[s_ * 8] = *(const uint4*)&F.W1t[s_ * 8];
  }

  {
    const int lrow = t >> 2;
    const int lcg  = (t & 3) * 16;
    const size_t gb = (size_t)(rowbase + lrow) * 64 + lcg;
    float xv[16];
    #pragma unroll
    for (int i = 0; i < 4; ++i) {
      const float4 a = ld4(&F.state[gb + i * 4]);
      const float4 b = ld4(&F.ao[gb + i * 4]);
      xv[i*4+0] = a.x + b.x; xv[i*4+1] = a.y + b.y;
      xv[i*4+2] = a.z + b.z; xv[i*4+3] = a.w + b.w;
    }
    float s1 = 0.f, s2 = 0.f;
    #pragma unroll
    for (int j = 0; j < 16; ++j) { s1 += xv[j]; s2 += xv[j] * xv[j]; }
    s1 += __shfl_xor(s1, 1, 64); s2 += __shfl_xor(s2, 1, 64);
    s1 += __shfl_xor(s1, 2, 64); s2 += __shfl_xor(s2, 2, 64);
    const float mean = s1 * (1.f / 64.f);
    const float rstd = rsqrtf(s2 * (1.f / 64.f) - mean * mean + EPS);
    float gv[16], bv[16];
    #pragma unroll
    for (int i = 0; i < 4; ++i) {
      *(float4*)&gv[i*4] = ld4(&F.g1[lcg + i * 4]);
      *(float4*)&bv[i*4] = ld4(&F.beta1[lcg + i * 4]);
    }
    #pragma unroll
    for (int h = 0; h < 2; ++h) {
      float z[8];
      #pragma unroll
      for (int j = 0; j < 8; ++j)
        z[j] = (xv[h*8+j] - mean) * rstd * gv[h*8+j] + bv[h*8+j];
      uint4 pkd;
      pkd.x = (unsigned)f2bf(z[0]) | ((unsigned)f2bf(z[1]) << 16);
      pkd.y = (unsigned)f2bf(z[2]) | ((unsigned)f2bf(z[3]) << 16);
      pkd.z = (unsigned)f2bf(z[4]) | ((unsigned)f2bf(z[5]) << 16);
      pkd.w = (unsigned)f2bf(z[6]) | ((unsigned)f2bf(z[7]) << 16);
      *(uint4*)((char*)Z2b + (lrow * 128 + (((lcg + h * 8) * 2) ^ ((lrow & 7) << 4)))) = pkd;
    }
  }
  __syncthreads();

  const int arow = w * 16 + lo;
  const int aswz = (lo & 7) << 4;

  s16x8 zf0, zf1;
  zf0 = *(const s16x8*)((const char*)Z2b + (arow * 128 + ((0 * 64 + hi * 16) ^ aswz)));
  zf1 = *(const s16x8*)((const char*)Z2b + (arow * 128 + ((1 * 64 + hi * 16) ^ aswz)));

  s16x8 pz[8];
  #pragma unroll
  for (int ps = 0; ps < 8; ++ps) {
    const int n0 = (2 * ps) * 16, n1 = (2 * ps + 1) * 16;
    const float4 bb0 = ld4(&F.b1[n0 + hi * 4]);
    const float4 bb1 = ld4(&F.b1[n1 + hi * 4]);
    f32x4 a0 = (f32x4){bb0.x, bb0.y, bb0.z, bb0.w};
    f32x4 a1 = (f32x4){bb1.x, bb1.y, bb1.z, bb1.w};
    #pragma unroll
    for (int ks = 0; ks < 2; ++ks) {
      const s16x8 zf = ks ? zf1 : zf0;
      const int na = n0 + lo, nb = n1 + lo;
      const s16x8 wfa = *(const s16x8*)((const char*)Wb + (na * 128 + ((ks * 64 + hi * 16) ^ ((na & 7) << 4))));
      const s16x8 wfb = *(const s16x8*)((const char*)Wb + (nb * 128 + ((ks * 64 + hi * 16) ^ ((nb & 7) << 4))));
      a0 = __builtin_amdgcn_mfma_f32_16x16x32_bf16(wfa, zf, a0, 0, 0, 0);
      a1 = __builtin_amdgcn_mfma_f32_16x16x32_bf16(wfb, zf, a1, 0, 0, 0);
    }
    float ga[8];
    #pragma unroll
    for (int e = 0; e < 8; ++e) {
      const float xg = (e < 4) ? a0[e & 3] : a1[e & 3];
      ga[e] = 0.5f * xg * (1.f + erff(xg * 0.70710678118654752f));
    }
    uint4 wv;
    wv.x = (unsigned)f2bf(ga[0]) | ((unsigned)f2bf(ga[1]) << 16);
    wv.y = (unsigned)f2bf(ga[2]) | ((unsigned)f2bf(ga[3]) << 16);
    wv.z = (unsigned)f2bf(ga[4]) | ((unsigned)f2bf(ga[5]) << 16);
    wv.w = (unsigned)f2bf(ga[6]) | ((unsigned)f2bf(ga[7]) << 16);
    pz[ps] = __builtin_bit_cast(s16x8, wv);
  }
  __syncthreads();

  #pragma unroll
  for (int i = 0; i < 8; ++i) {
    const int s_ = i * 256 + t;
    *(uint4*)&Wb[s_ * 8] = *(const uint4*)&F.W2t[s_ * 8];
  }
  __syncthreads();

  f32x4 acc2[4];
  #pragma unroll
  for (int nt = 0; nt < 4; ++nt) { const float b = F.b2[nt * 16 + lo]; acc2[nt] = (f32x4){b, b, b, b}; }
  #pragma unroll
  for (int ps = 0; ps < 8; ++ps) {
    #pragma unroll
    for (int nt = 0; nt < 4; ++nt) {
      const s16x8 bf = *(const s16x8*)&Wb[((ps * 4 + nt) * 64 + lane) * 8];
      acc2[nt] = __builtin_amdgcn_mfma_f32_16x16x32_bf16(pz[ps], bf, acc2[nt], 0, 0, 0);
    }
  }

  #pragma unroll
  for (int nt = 0; nt < 4; ++nt) {
    #pragma unroll
    for (int r = 0; r < 4; ++r) {
      const int grow = rowbase + w * 16 + hi * 4 + r;
      const int col = nt * 16 + lo;
      const size_t gidx = (size_t)grow * 64 + col;
      const float z1 = F.state[gidx] + F.ao[gidx];
      F.out[gidx] = z1 + acc2[nt][r];
    }
  }
}

} // namespace

extern "C" void kernel_launch(void* const* d_in, const int* in_sizes, int n_in,
                              void* d_out, int out_size, void* d_ws, size_t ws_size,
                              hipStream_t stream)
{
  const float* state = (const float*)d_in[0];
  const float* H     = (const float*)d_in[1];
  const float* Wq  = (const float*)d_in[2];  const float* bq  = (const float*)d_in[3];
  const float* Wk  = (const float*)d_in[4];  const float* bk  = (const float*)d_in[5];
  const float* Wv  = (const float*)d_in[6];  const float* bv  = (const float*)d_in[7];
  const float* Wcq = (const float*)d_in[8];  const float* bcq = (const float*)d_in[9];
  const float* Wck = (const float*)d_in[10]; const float* bck = (const float*)d_in[11];
  const float* Wcv = (const float*)d_in[12]; const float* bcv = (const float*)d_in[13];
  const float* gQE = (const float*)d_in[14]; const float* betaQE = (const float*)d_in[15];
  const float* gKE = (const float*)d_in[16]; const float* betaKE = (const float*)d_in[17];
  const float* gVE = (const float*)d_in[18]; const float* betaVE = (const float*)d_in[19];
  const float* gQH = (const float*)d_in[20]; const float* betaQH = (const float*)d_in[21];
  const float* gKH = (const float*)d_in[22]; const float* betaKH = (const float*)d_in[23];
  const float* gVH = (const float*)d_in[24]; const float* betaVH = (const float*)d_in[25];
  const float* W1 = (const float*)d_in[26]; const float* b1 = (const float*)d_in[27];
  const float* W2 = (const float*)d_in[28]; const float* b2 = (const float*)d_in[29];
  const float* g1 = (const float*)d_in[30]; const float* beta1 = (const float*)d_in[31];

  constexpr size_t QKV_E = (size_t)NBAT * 2 * 300 * 32;   // 4,915,200 bf16 per tensor
  float*  ao_ws = (float*)d_ws;                           // [ROWS][64] fp32
  ushort* q_ws  = (ushort*)(ao_ws + (size_t)ROWS * DM);
  ushort* k_ws  = q_ws + QKV_E;
  ushort* v_ws  = k_ws + QKV_E;
  ushort* Bqkv  = v_ws + QKV_E;        // 61440
  ushort* W1t   = Bqkv + 61440;        // 16384
  ushort* W2t   = W1t + 16384;         // 16384
  float*  pk    = (float*)(W2t + 16384);  // 1152 floats

  PrepArgs P;
  P.Wq = Wq; P.Wk = Wk; P.Wv = Wv; P.Wcq = Wcq; P.Wck = Wck; P.Wcv = Wcv;
  P.bq = bq; P.bk = bk; P.bv = bv; P.bcq = bcq; P.bck = bck; P.bcv = bcv;
  P.gQE = gQE; P.betaQE = betaQE; P.gKE = gKE; P.betaKE = betaKE;
  P.gVE = gVE; P.betaVE = betaVE; P.gQH = gQH; P.betaQH = betaQH;
  P.gKH = gKH; P.betaKH = betaKH; P.gVH = gVH; P.betaVH = betaVH;
  P.W1 = W1; P.W2 = W2;
  P.Bqkv = Bqkv; P.W1t = W1t; P.W2t = W2t; P.pk = pk;
  tb_prep<<<373, 256, 0, stream>>>(P);

  QkvArgs A;
  A.state = state; A.H = H; A.Bqkv = Bqkv; A.pk = pk;
  A.qo = q_ws; A.ko = k_ws; A.vo = v_ws;
  tb_qkv<<<ROWS / 64, 256, 0, stream>>>(A);

  tb_attn<<<dim3(2, NBAT), 256, 0, stream>>>(q_ws, k_ws, v_ws, ao_ws);

  FfnArgs F;
  F.state = state; F.ao = ao_ws; F.W1t = W1t; F.W2t = W2t;
  F.b1 = b1; F.b2 = b2; F.g1 = g1; F.beta1 = beta1; F.out = (float*)d_out;
  tb_ffn<<<ROWS / 64, 256, 0, stream>>>(F);
}

// Round 13
// 111.509 us; speedup vs baseline: 1.1890x; 1.1371x over previous
//
#include <hip/hip_runtime.h>
#include <math.h>

namespace {

constexpr int SEQ  = 300;
constexpr int DM   = 64;
constexpr int DFFN = 256;
constexpr int NBAT = 256;
constexpr int ROWS = NBAT * SEQ;   // 76800
constexpr float EPS = 1e-5f;

typedef __attribute__((ext_vector_type(8))) short s16x8;
typedef __attribute__((ext_vector_type(4))) float f32x4;

__device__ __forceinline__ float4 ld4(const float* p) { return *reinterpret_cast<const float4*>(p); }

__device__ __forceinline__ ushort f2bf(float x) {
  unsigned u = __builtin_bit_cast(unsigned, x);
  u += 0x7FFFu + ((u >> 16) & 1u);
  return (ushort)(u >> 16);
}

// Abramowitz-Stegun 7.1.26 rational erf approximation, |abs err| <= 1.5e-7.
// ~12 VALU + 1 v_exp vs libm erff's branchy ~40-instr path. Error is ~4000x
// below the bf16 quantization applied to the GELU output downstream.
__device__ __forceinline__ float erf_fast(float x) {
  const float ax = fabsf(x);
  const float t = 1.0f / (1.0f + 0.3275911f * ax);
  float p = 1.061405429f;
  p = fmaf(p, t, -1.453152027f);
  p = fmaf(p, t, 1.421413741f);
  p = fmaf(p, t, -0.284496736f);
  p = fmaf(p, t, 0.254829592f);
  const float r = 1.0f - p * t * __expf(-ax * ax);
  return copysignf(r, x);
}

// ---------------------------------------------------------------------------
// Prep (verified, unchanged)
// ---------------------------------------------------------------------------
struct PrepArgs {
  const float *Wq,*Wk,*Wv,*Wcq,*Wck,*Wcv;
  const float *bq,*bk,*bv,*bcq,*bck,*bcv;
  const float *gQE,*betaQE,*gKE,*betaKE,*gVE,*betaVE;
  const float *gQH,*betaQH,*gKH,*betaKH,*gVH,*betaVH;
  const float *W1,*W2;
  ushort *Bqkv, *W1t, *W2t;
  float *pk;   // bE[192] bH[192] gE[192] betaE[192] gH[192] betaH[192]
};

__global__ __launch_bounds__(256) void tb_prep(PrepArgs P) {
  const int idx = blockIdx.x * 256 + threadIdx.x;
  if (idx < 61440) {                       // Bqkv [5 chunks][192 n][64 k]
    const int c = idx / 12288, rem = idx % 12288;
    const int n = rem >> 6, k = rem & 63;
    const int br = n >> 6, col = n & 63;
    float v;
    if (c == 0) {
      const float* W = (br == 0) ? P.Wq : (br == 1) ? P.Wk : P.Wv;
      v = W[k * DM + col];
    } else {
      const float* W = (br == 0) ? P.Wcq : (br == 1) ? P.Wck : P.Wcv;
      v = W[((c - 1) * 64 + k) * DM + col];
    }
    P.Bqkv[c * 12288 + ((n * 128 + ((k * 2) ^ ((n & 7) << 4))) >> 1)] = f2bf(v);
  } else if (idx < 77824) {                // W1t [256 n][64 k] swizzled rows
    const int r = idx - 61440, n = r >> 6, k = r & 63;
    P.W1t[(n * 128 + ((k * 2) ^ ((n & 7) << 4))) >> 1] = f2bf(P.W1[k * DFFN + n]);
  } else if (idx < 94208) {                // W2t fragments [ps 0..7][nt2 0..3][lane][8]
    const int j = idx - 77824;
    const int fragId = j >> 9, within = j & 511;
    const int lane = within >> 3, e = within & 7;
    const int ps = fragId >> 2, nt2 = fragId & 3;
    const int n = nt2 * 16 + (lane & 15);
    const int k = ps * 32 + ((e >> 2) << 4) + ((lane >> 4) << 2) + (e & 3);
    P.W2t[j] = f2bf(P.W2[k * DM + n]);
  } else if (idx < 95360) {                // packed bias/LN params
    const int r = idx - 94208, which = r / 192, j = r % 192;
    const int br = j >> 6, col = j & 63;
    const float* s;
    switch (which) {
      case 0:  s = (br==0)?P.bq   :(br==1)?P.bk    :P.bv;     break;
      case 1:  s = (br==0)?P.bcq  :(br==1)?P.bck   :P.bcv;    break;
      case 2:  s = (br==0)?P.gQE  :(br==1)?P.gKE   :P.gVE;    break;
      case 3:  s = (br==0)?P.betaQE:(br==1)?P.betaKE:P.betaVE; break;
      case 4:  s = (br==0)?P.gQH  :(br==1)?P.gKH   :P.gVH;    break;
      default: s = (br==0)?P.betaQH:(br==1)?P.betaKH:P.betaVH; break;
    }
    P.pk[which * 192 + j] = s[col];
  }
}

// ---------------------------------------------------------------------------
// K1: q/k/v via MFMA (R6-verified, byte-identical).
// ---------------------------------------------------------------------------
struct QkvArgs {
  const float *state, *H;
  const ushort *Bqkv;
  const float *pk;
  ushort *qo, *ko, *vo;  // q,k: [bh][300][32] ; v: [bh][32][300]
};

__global__ __launch_bounds__(256) void tb_qkv(QkvArgs A) {
  __shared__ __align__(16) ushort Ab[4608];    // A chunk [64][64] swizzled (+V xpose buf)
  __shared__ __align__(16) ushort Bb[12288];   // B chunk [192][64] swizzled
  const int t = threadIdx.x;
  const int lane = t & 63, w = t >> 6;
  const int lo = lane & 15, hi = lane >> 4;
  const int rowbase = blockIdx.x * 64;

  f32x4 accE[12], accH[12];
  #pragma unroll
  for (int nt = 0; nt < 12; ++nt) {
    const float bE = A.pk[nt * 16 + lo], bH = A.pk[192 + nt * 16 + lo];
    accE[nt] = (f32x4){bE, bE, bE, bE};
    accH[nt] = (f32x4){bH, bH, bH, bH};
  }

  const int arow = w * 16 + lo;
  const int aswz = (lo & 7) << 4;

#define STAGE_B(c)                                                            \
  _Pragma("unroll")                                                           \
  for (int i = 0; i < 6; ++i) {                                               \
    const int s_ = i * 256 + t;                                               \
    *(uint4*)&Bb[s_ * 8] = *(const uint4*)&A.Bqkv[(c) * 12288 + s_ * 8];      \
  }

#define STAGE_A(SRC, STRIDE)                                                  \
  _Pragma("unroll")                                                           \
  for (int i = 0; i < 4; ++i) {                                               \
    const int p_ = i * 256 + t;                                               \
    const int row_ = p_ >> 4, slot_ = p_ & 15;                                \
    const float4 f_ = ld4(&(SRC)[row_ * (STRIDE) + slot_ * 4]);               \
    ushort4 u_;                                                               \
    u_.x = f2bf(f_.x); u_.y = f2bf(f_.y); u_.z = f2bf(f_.z); u_.w = f2bf(f_.w);\
    *(ushort4*)((char*)Ab + (row_ * 128 + ((slot_ * 8) ^ ((row_ & 7) << 4)))) = u_; \
  }

#define COMPUTE(ACC)                                                          \
  _Pragma("unroll")                                                           \
  for (int ks = 0; ks < 2; ++ks) {                                            \
    const s16x8 af = *(const s16x8*)((const char*)Ab +                        \
        (arow * 128 + ((ks * 64 + hi * 16) ^ aswz)));                         \
    _Pragma("unroll")                                                         \
    for (int nt = 0; nt < 12; ++nt) {                                         \
      const int n_ = nt * 16 + lo;                                            \
      const s16x8 bf = *(const s16x8*)((const char*)Bb +                      \
          (n_ * 128 + ((ks * 64 + hi * 16) ^ ((n_ & 7) << 4))));              \
      ACC[nt] = __builtin_amdgcn_mfma_f32_16x16x32_bf16(af, bf, ACC[nt], 0, 0, 0); \
    }                                                                         \
  }

  STAGE_B(0)
  STAGE_A(A.state + (size_t)rowbase * 64, 64)
  __syncthreads();
  COMPUTE(accE)
  for (int c = 1; c < 5; ++c) {
    __syncthreads();
    STAGE_B(c)
    const float* hsrc = A.H + (size_t)rowbase * 256 + (c - 1) * 64;
    STAGE_A(hsrc, 256)
    __syncthreads();
    COMPUTE(accH)
  }
#undef STAGE_B
#undef STAGE_A
#undef COMPUTE

  const float* gE  = A.pk + 384;
  const float* bEt = A.pk + 576;
  const float* gH  = A.pk + 768;
  const float* bHt = A.pk + 960;
  const int growbase = rowbase + w * 16 + hi * 4;
  float vout[4][4];

  #pragma unroll
  for (int br = 0; br < 3; ++br) {
    #pragma unroll
    for (int r = 0; r < 4; ++r) {
      float s1 = 0.f, s2 = 0.f, u1 = 0.f, u2 = 0.f;
      #pragma unroll
      for (int qq = 0; qq < 4; ++qq) {
        const float ev = accE[br * 4 + qq][r], hv = accH[br * 4 + qq][r];
        s1 += ev; s2 += ev * ev; u1 += hv; u2 += hv * hv;
      }
      #pragma unroll
      for (int m = 1; m <= 8; m <<= 1) {
        s1 += __shfl_xor(s1, m, 64); s2 += __shfl_xor(s2, m, 64);
        u1 += __shfl_xor(u1, m, 64); u2 += __shfl_xor(u2, m, 64);
      }
      const float me = s1 * (1.f / 64.f);
      const float re = rsqrtf(s2 * (1.f / 64.f) - me * me + EPS);
      const float mh = u1 * (1.f / 64.f);
      const float rh = rsqrtf(u2 * (1.f / 64.f) - mh * mh + EPS);
      const int grow = growbase + r;
      const int bb = grow / 300, ss = grow - bb * 300;
      #pragma unroll
      for (int qq = 0; qq < 4; ++qq) {
        const int colg = (br * 4 + qq) * 16 + lo;
        const float en = (accE[br * 4 + qq][r] - me) * re * gE[colg] + bEt[colg];
        const float hn = (accH[br * 4 + qq][r] - mh) * rh * gH[colg] + bHt[colg];
        const float val = en * hn;
        if (br == 2) {
          vout[r][qq] = val;
        } else {
          const int cb = qq * 16 + lo;
          const int hh = cb >> 5, dk = cb & 31;
          ushort* dst = (br == 0) ? A.qo : A.ko;
          const float sc = (br == 0) ? 0.17677669529663687f : 1.f;
          dst[((size_t)(bb * 2 + hh) * 300 + ss) * 32 + dk] = f2bf(val * sc);
        }
      }
    }
  }

  __syncthreads();
  ushort* vbuf = Ab;  // [64 dk][68 s]
  #pragma unroll
  for (int r = 0; r < 4; ++r) {
    const int sl = w * 16 + hi * 4 + r;
    #pragma unroll
    for (int qq = 0; qq < 4; ++qq) {
      const int dk = qq * 16 + lo;
      vbuf[dk * 68 + sl] = f2bf(vout[r][qq]);
    }
  }
  __syncthreads();
  #pragma unroll
  for (int i = 0; i < 4; ++i) {
    const int p = i * 256 + t;
    const int dk = p >> 4, sg = p & 15;
    const int grow = rowbase + sg * 4;
    const int bb = grow / 300, ss = grow - bb * 300;
    const int hh = dk >> 5, dkh = dk & 31;
    ushort4 val;
    val.x = vbuf[dk * 68 + sg * 4 + 0];
    val.y = vbuf[dk * 68 + sg * 4 + 1];
    val.z = vbuf[dk * 68 + sg * 4 + 2];
    val.w = vbuf[dk * 68 + sg * 4 + 3];
    *(ushort4*)&A.vo[(size_t)(bb * 2 + hh) * 9600 + dkh * 300 + ss] = val;
  }
}

// ---------------------------------------------------------------------------
// K2: bf16 MFMA attention (R10-verified: Q fragments direct from global,
// 39.5KB LDS). Zero-fill for rows 300..303 via per-lane predication.
// ---------------------------------------------------------------------------
__global__ __launch_bounds__(256, 2) void tb_attn(const ushort* __restrict__ q,
    const ushort* __restrict__ k, const ushort* __restrict__ vt, float* __restrict__ ao)
{
  __shared__ __align__(16) char lk[304 * 64];
  __shared__ __align__(16) char lv[32 * 656];

  const int t = threadIdx.x;
  const int hh = blockIdx.x, b = blockIdx.y;
  const size_t bh = (size_t)(b * 2 + hh);

  const char* qg = (const char*)(q + bh * 300 * 32);
  const char* kg = (const char*)(k + bh * 300 * 32);
  const char* vg = (const char*)(vt + bh * 32 * 300);

  for (int c = t; c < 1216; c += 256) {
    const int lin = c * 16;
    const int row = c >> 2;
    uint4 val = make_uint4(0u, 0u, 0u, 0u);
    if (row < 300) val = *(const uint4*)(kg + lin);
    *(uint4*)(lk + (lin ^ ((lin >> 2) & 0x70))) = val;
  }
  for (int i = t; i < 320; i += 256) {
    const int row = i / 10, cc = i - row * 10;
    *(unsigned*)(lv + row * 656 + 600 + cc * 4) = 0u;
  }
  for (int i = t; i < 2400; i += 256) {
    const int row = i / 75, cc = i - row * 75;
    *(uint2*)(lv + row * 656 + cc * 8) = *(const uint2*)(vg + row * 600 + cc * 8);
  }
  __syncthreads();

  const int lane = t & 63, wid = t >> 6;
  const int lo = lane & 15, hi = lane >> 4;
  const f32x4 zero = {0.f, 0.f, 0.f, 0.f};

  for (int qt = wid; qt < 19; qt += 4) {
    const int qrow = qt * 16 + lo;
    s16x8 qf = __builtin_bit_cast(s16x8, make_uint4(0u, 0u, 0u, 0u));
    if (qrow < 300) qf = *(const s16x8*)(qg + qrow * 64 + hi * 16);

    f32x4 p[19];
    #pragma unroll
    for (int kt = 0; kt < 19; ++kt) {
      int ka = (kt * 16 + lo) * 64 + hi * 16;
      ka ^= (ka >> 2) & 0x70;
      const s16x8 kf = *(const s16x8*)(lk + ka);
      p[kt] = __builtin_amdgcn_mfma_f32_16x16x32_bf16(kf, qf, zero, 0, 0, 0);
    }

    float mx = -1e30f;
    #pragma unroll
    for (int kt = 0; kt < 19; ++kt)
      #pragma unroll
      for (int r = 0; r < 4; ++r) mx = fmaxf(mx, p[kt][r]);
    mx = fmaxf(mx, __shfl_xor(mx, 16, 64));
    mx = fmaxf(mx, __shfl_xor(mx, 32, 64));

    #pragma unroll
    for (int kt = 0; kt < 19; ++kt)
      #pragma unroll
      for (int r = 0; r < 4; ++r) p[kt][r] = __expf(p[kt][r] - mx);
    if (hi == 3) p[18] = zero;

    float sum = 0.f;
    #pragma unroll
    for (int kt = 0; kt < 19; ++kt)
      #pragma unroll
      for (int r = 0; r < 4; ++r) sum += p[kt][r];
    sum += __shfl_xor(sum, 16, 64);
    sum += __shfl_xor(sum, 32, 64);
    const float inv = 1.f / sum;

    s16x8 pb[10];
    #pragma unroll
    for (int pr = 0; pr < 9; ++pr) {
      uint4 wv;
      wv.x = (unsigned)f2bf(p[2*pr][0] * inv)   | ((unsigned)f2bf(p[2*pr][1] * inv) << 16);
      wv.y = (unsigned)f2bf(p[2*pr][2] * inv)   | ((unsigned)f2bf(p[2*pr][3] * inv) << 16);
      wv.z = (unsigned)f2bf(p[2*pr+1][0] * inv) | ((unsigned)f2bf(p[2*pr+1][1] * inv) << 16);
      wv.w = (unsigned)f2bf(p[2*pr+1][2] * inv) | ((unsigned)f2bf(p[2*pr+1][3] * inv) << 16);
      pb[pr] = __builtin_bit_cast(s16x8, wv);
    }
    {
      uint4 wv;
      wv.x = (unsigned)f2bf(p[18][0] * inv) | ((unsigned)f2bf(p[18][1] * inv) << 16);
      wv.y = (unsigned)f2bf(p[18][2] * inv) | ((unsigned)f2bf(p[18][3] * inv) << 16);
      wv.z = 0u; wv.w = 0u;
      pb[9] = __builtin_bit_cast(s16x8, wv);
    }

    f32x4 acc0 = zero, acc1 = zero;
    #pragma unroll
    for (int pr = 0; pr < 10; ++pr) {
      const int byte0 = pr * 64 + hi * 8;
      uint4 w0, w1;
      {
        const uint2 a = *(const uint2*)(lv + lo * 656 + byte0);
        const uint2 c = *(const uint2*)(lv + lo * 656 + byte0 + 32);
        w0.x = a.x; w0.y = a.y; w0.z = c.x; w0.w = c.y;
      }
      {
        const uint2 a = *(const uint2*)(lv + (lo + 16) * 656 + byte0);
        const uint2 c = *(const uint2*)(lv + (lo + 16) * 656 + byte0 + 32);
        w1.x = a.x; w1.y = a.y; w1.z = c.x; w1.w = c.y;
      }
      acc0 = __builtin_amdgcn_mfma_f32_16x16x32_bf16(pb[pr], __builtin_bit_cast(s16x8, w0), acc0, 0, 0, 0);
      acc1 = __builtin_amdgcn_mfma_f32_16x16x32_bf16(pb[pr], __builtin_bit_cast(s16x8, w1), acc1, 0, 0, 0);
    }

    float* aop = ao + ((size_t)b * 300) * 64 + hh * 32;
    const int s0 = qt * 16 + hi * 4;
    #pragma unroll
    for (int r = 0; r < 4; ++r) {
      const int s = s0 + r;
      if (s < 300) {
        aop[s * 64 + lo]      = acc0[r];
        aop[s * 64 + 16 + lo] = acc1[r];
      }
    }
  }
}

// ---------------------------------------------------------------------------
// K3: FFN via MFMA (R6-verified structure; ONE change: libm erff -> A-S
// 7.1.26 erf_fast, |abs err| <= 1.5e-7, ~4000x below Z3's bf16 rounding).
// ---------------------------------------------------------------------------
struct FfnArgs {
  const float *state, *ao;
  const ushort *W1t, *W2t;
  const float *b1, *b2, *g1, *beta1;
  float* out;
};

__global__ __launch_bounds__(256) void tb_ffn(FfnArgs F) {
  __shared__ __align__(16) ushort Z2b[4096];    // [64][64] swizzled (8KB), wave-private rows
  __shared__ __align__(16) ushort Wb[16384];    // W1t, then W2 fragments (32KB)
  const int t = threadIdx.x;
  const int lane = t & 63, w = t >> 6;
  const int lo = lane & 15, hi = lane >> 4;
  const int rowbase = blockIdx.x * 64;

  #pragma unroll
  for (int i = 0; i < 8; ++i) {
    const int s_ = i * 256 + t;
    *(uint4*)&Wb[s_ * 8] = *(const uint4*)&F.W1t[s_ * 8];
  }

  {
    const int lrow = t >> 2;
    const int lcg  = (t & 3) * 16;
    const size_t gb = (size_t)(rowbase + lrow) * 64 + lcg;
    float xv[16];
    #pragma unroll
    for (int i = 0; i < 4; ++i) {
      const float4 a = ld4(&F.state[gb + i * 4]);
      const float4 b = ld4(&F.ao[gb + i * 4]);
      xv[i*4+0] = a.x + b.x; xv[i*4+1] = a.y + b.y;
      xv[i*4+2] = a.z + b.z; xv[i*4+3] = a.w + b.w;
    }
    float s1 = 0.f, s2 = 0.f;
    #pragma unroll
    for (int j = 0; j < 16; ++j) { s1 += xv[j]; s2 += xv[j] * xv[j]; }
    s1 += __shfl_xor(s1, 1, 64); s2 += __shfl_xor(s2, 1, 64);
    s1 += __shfl_xor(s1, 2, 64); s2 += __shfl_xor(s2, 2, 64);
    const float mean = s1 * (1.f / 64.f);
    const float rstd = rsqrtf(s2 * (1.f / 64.f) - mean * mean + EPS);
    float gv[16], bv[16];
    #pragma unroll
    for (int i = 0; i < 4; ++i) {
      *(float4*)&gv[i*4] = ld4(&F.g1[lcg + i * 4]);
      *(float4*)&bv[i*4] = ld4(&F.beta1[lcg + i * 4]);
    }
    #pragma unroll
    for (int h = 0; h < 2; ++h) {
      float z[8];
      #pragma unroll
      for (int j = 0; j < 8; ++j)
        z[j] = (xv[h*8+j] - mean) * rstd * gv[h*8+j] + bv[h*8+j];
      uint4 pkd;
      pkd.x = (unsigned)f2bf(z[0]) | ((unsigned)f2bf(z[1]) << 16);
      pkd.y = (unsigned)f2bf(z[2]) | ((unsigned)f2bf(z[3]) << 16);
      pkd.z = (unsigned)f2bf(z[4]) | ((unsigned)f2bf(z[5]) << 16);
      pkd.w = (unsigned)f2bf(z[6]) | ((unsigned)f2bf(z[7]) << 16);
      *(uint4*)((char*)Z2b + (lrow * 128 + (((lcg + h * 8) * 2) ^ ((lrow & 7) << 4)))) = pkd;
    }
  }
  __syncthreads();

  const int arow = w * 16 + lo;
  const int aswz = (lo & 7) << 4;

  s16x8 zf0, zf1;
  zf0 = *(const s16x8*)((const char*)Z2b + (arow * 128 + ((0 * 64 + hi * 16) ^ aswz)));
  zf1 = *(const s16x8*)((const char*)Z2b + (arow * 128 + ((1 * 64 + hi * 16) ^ aswz)));

  s16x8 pz[8];
  #pragma unroll
  for (int ps = 0; ps < 8; ++ps) {
    const int n0 = (2 * ps) * 16, n1 = (2 * ps + 1) * 16;
    const float4 bb0 = ld4(&F.b1[n0 + hi * 4]);
    const float4 bb1 = ld4(&F.b1[n1 + hi * 4]);
    f32x4 a0 = (f32x4){bb0.x, bb0.y, bb0.z, bb0.w};
    f32x4 a1 = (f32x4){bb1.x, bb1.y, bb1.z, bb1.w};
    #pragma unroll
    for (int ks = 0; ks < 2; ++ks) {
      const s16x8 zf = ks ? zf1 : zf0;
      const int na = n0 + lo, nb = n1 + lo;
      const s16x8 wfa = *(const s16x8*)((const char*)Wb + (na * 128 + ((ks * 64 + hi * 16) ^ ((na & 7) << 4))));
      const s16x8 wfb = *(const s16x8*)((const char*)Wb + (nb * 128 + ((ks * 64 + hi * 16) ^ ((nb & 7) << 4))));
      a0 = __builtin_amdgcn_mfma_f32_16x16x32_bf16(wfa, zf, a0, 0, 0, 0);
      a1 = __builtin_amdgcn_mfma_f32_16x16x32_bf16(wfb, zf, a1, 0, 0, 0);
    }
    float ga[8];
    #pragma unroll
    for (int e = 0; e < 8; ++e) {
      const float xg = (e < 4) ? a0[e & 3] : a1[e & 3];
      ga[e] = 0.5f * xg * (1.f + erf_fast(xg * 0.70710678118654752f));
    }
    uint4 wv;
    wv.x = (unsigned)f2bf(ga[0]) | ((unsigned)f2bf(ga[1]) << 16);
    wv.y = (unsigned)f2bf(ga[2]) | ((unsigned)f2bf(ga[3]) << 16);
    wv.z = (unsigned)f2bf(ga[4]) | ((unsigned)f2bf(ga[5]) << 16);
    wv.w = (unsigned)f2bf(ga[6]) | ((unsigned)f2bf(ga[7]) << 16);
    pz[ps] = __builtin_bit_cast(s16x8, wv);
  }
  __syncthreads();

  #pragma unroll
  for (int i = 0; i < 8; ++i) {
    const int s_ = i * 256 + t;
    *(uint4*)&Wb[s_ * 8] = *(const uint4*)&F.W2t[s_ * 8];
  }
  __syncthreads();

  f32x4 acc2[4];
  #pragma unroll
  for (int nt = 0; nt < 4; ++nt) { const float b = F.b2[nt * 16 + lo]; acc2[nt] = (f32x4){b, b, b, b}; }
  #pragma unroll
  for (int ps = 0; ps < 8; ++ps) {
    #pragma unroll
    for (int nt = 0; nt < 4; ++nt) {
      const s16x8 bf = *(const s16x8*)&Wb[((ps * 4 + nt) * 64 + lane) * 8];
      acc2[nt] = __builtin_amdgcn_mfma_f32_16x16x32_bf16(pz[ps], bf, acc2[nt], 0, 0, 0);
    }
  }

  #pragma unroll
  for (int nt = 0; nt < 4; ++nt) {
    #pragma unroll
    for (int r = 0; r < 4; ++r) {
      const int grow = rowbase + w * 16 + hi * 4 + r;
      const int col = nt * 16 + lo;
      const size_t gidx = (size_t)grow * 64 + col;
      const float z1 = F.state[gidx] + F.ao[gidx];
      F.out[gidx] = z1 + acc2[nt][r];
    }
  }
}

} // namespace

extern "C" void kernel_launch(void* const* d_in, const int* in_sizes, int n_in,
                              void* d_out, int out_size, void* d_ws, size_t ws_size,
                              hipStream_t stream)
{
  const float* state = (const float*)d_in[0];
  const float* H     = (const float*)d_in[1];
  const float* Wq  = (const float*)d_in[2];  const float* bq  = (const float*)d_in[3];
  const float* Wk  = (const float*)d_in[4];  const float* bk  = (const float*)d_in[5];
  const float* Wv  = (const float*)d_in[6];  const float* bv  = (const float*)d_in[7];
  const float* Wcq = (const float*)d_in[8];  const float* bcq = (const float*)d_in[9];
  const float* Wck = (const float*)d_in[10]; const float* bck = (const float*)d_in[11];
  const float* Wcv = (const float*)d_in[12]; const float* bcv = (const float*)d_in[13];
  const float* gQE = (const float*)d_in[14]; const float* betaQE = (const float*)d_in[15];
  const float* gKE = (const float*)d_in[16]; const float* betaKE = (const float*)d_in[17];
  const float* gVE = (const float*)d_in[18]; const float* betaVE = (const float*)d_in[19];
  const float* gQH = (const float*)d_in[20]; const float* betaQH = (const float*)d_in[21];
  const float* gKH = (const float*)d_in[22]; const float* betaKH = (const float*)d_in[23];
  const float* gVH = (const float*)d_in[24]; const float* betaVH = (const float*)d_in[25];
  const float* W1 = (const float*)d_in[26]; const float* b1 = (const float*)d_in[27];
  const float* W2 = (const float*)d_in[28]; const float* b2 = (const float*)d_in[29];
  const float* g1 = (const float*)d_in[30]; const float* beta1 = (const float*)d_in[31];

  constexpr size_t QKV_E = (size_t)NBAT * 2 * 300 * 32;   // 4,915,200 bf16 per tensor
  float*  ao_ws = (float*)d_ws;                           // [ROWS][64] fp32
  ushort* q_ws  = (ushort*)(ao_ws + (size_t)ROWS * DM);
  ushort* k_ws  = q_ws + QKV_E;
  ushort* v_ws  = k_ws + QKV_E;
  ushort* Bqkv  = v_ws + QKV_E;        // 61440
  ushort* W1t   = Bqkv + 61440;        // 16384
  ushort* W2t   = W1t + 16384;         // 16384
  float*  pk    = (float*)(W2t + 16384);  // 1152 floats

  PrepArgs P;
  P.Wq = Wq; P.Wk = Wk; P.Wv = Wv; P.Wcq = Wcq; P.Wck = Wck; P.Wcv = Wcv;
  P.bq = bq; P.bk = bk; P.bv = bv; P.bcq = bcq; P.bck = bck; P.bcv = bcv;
  P.gQE = gQE; P.betaQE = betaQE; P.gKE = gKE; P.betaKE = betaKE;
  P.gVE = gVE; P.betaVE = betaVE; P.gQH = gQH; P.betaQH = betaQH;
  P.gKH = gKH; P.betaKH = betaKH; P.gVH = gVH; P.betaVH = betaVH;
  P.W1 = W1; P.W2 = W2;
  P.Bqkv = Bqkv; P.W1t = W1t; P.W2t = W2t; P.pk = pk;
  tb_prep<<<373, 256, 0, stream>>>(P);

  QkvArgs A;
  A.state = state; A.H = H; A.Bqkv = Bqkv; A.pk = pk;
  A.qo = q_ws; A.ko = k_ws; A.vo = v_ws;
  tb_qkv<<<ROWS / 64, 256, 0, stream>>>(A);

  tb_attn<<<dim3(2, NBAT), 256, 0, stream>>>(q_ws, k_ws, v_ws, ao_ws);

  FfnArgs F;
  F.state = state; F.ao = ao_ws; F.W1t = W1t; F.W2t = W2t;
  F.b1 = b1; F.b2 = b2; F.g1 = g1; F.beta1 = beta1; F.out = (float*)d_out;
  tb_ffn<<<ROWS / 64, 256, 0, stream>>>(F);
}